// Round 10
// baseline (310.987 us; speedup 1.0000x reference)
//
#include <hip/hip_runtime.h>
#include <hip/hip_fp16.h>
#include <math.h>

#define NT 100000
#define B_GRAPHS 50
#define NE 1600000
#define V 15000
#define D 128
#define NODES_PER_GRAPH (NT / B_GRAPHS)   // 2000

#define POOL_N (B_GRAPHS * D + B_GRAPHS)  // 6450

#define BSH 8
#define BIN_DSTS 256
#define NBIN ((NT + BIN_DSTS - 1) / BIN_DSTS)   // 391
#define SLACK (3 * BIN_DSTS)                    // 768 (worst-case row padding)
#define EPB 4096                                // edges per k_binfill block
#define NFB ((NE + EPB - 1) / EPB)              // 391
#define BUF_SORT 5632                           // per-bin LDS record cap
#define PAY_CAP2 (NE + NBIN * (SLACK + 4) + 512)

#define A2_BPG 32                               // k_agg2 blocks per graph

// ---- e5m2 helpers: code = top byte of fp16 (RN). decode = byte<<8 as half ----
__device__ __forceinline__ unsigned enc2_e5m2(float a, float b) {
  unsigned ha = __half_as_ushort(__float2half(a));
  unsigned hb = __half_as_ushort(__float2half(b));
  ha = ((ha + 0x7fu + ((ha >> 8) & 1u)) >> 8) & 0xffu;
  hb = ((hb + 0x7fu + ((hb >> 8) & 1u)) >> 8) & 0xffu;
  return ha | (hb << 8);
}
__device__ __forceinline__ unsigned enc4_e5m2(float a, float b, float c, float d) {
  return enc2_e5m2(a, b) | (enc2_e5m2(c, d) << 16);
}
__device__ __forceinline__ float4 dec4_e5m2(unsigned u) {
  unsigned hp0 = ((u & 0xffu) << 8) | ((u & 0xff00u) << 16);      // dims d, d+1
  unsigned hp1 = ((u >> 8) & 0xff00u) | (u & 0xff000000u);        // dims d+2, d+3
  __half2 h0 = *(__half2*)&hp0;
  __half2 h1 = *(__half2*)&hp1;
  float2 f0 = __half22float2(h0);
  float2 f1 = __half22float2(h1);
  return make_float4(f0.x, f0.y, f1.x, f1.y);
}

// ---------- K1: P1p8 = e5m2(embeds @ W1 + b1)  [V, 32 uints] ----------
#define PR 16
__global__ __launch_bounds__(256, 8)
void k_project(const float* __restrict__ embeds,
               const float* __restrict__ W1,
               const float* __restrict__ b1,
               unsigned* __restrict__ P1p8) {
  __shared__ float sE[PR][D];          // 8 KB
  __shared__ float sO[PR][D];          // 8 KB
  int t = threadIdx.x;
  int row0 = blockIdx.x * PR;
  for (int i = t; i < PR * D; i += 256) {
    int r = i >> 7, c = i & 127;
    int v = row0 + r;
    sE[r][c] = (v < V) ? embeds[(size_t)v * D + c] : 0.f;
  }
  __syncthreads();
  int c = t & 127, rg = (t >> 7) * 8;  // this thread: col c, rows rg..rg+7
  float bd = b1[c];
  float acc[8];
#pragma unroll
  for (int r = 0; r < 8; ++r) acc[r] = bd;
#pragma unroll 4
  for (int k = 0; k < D; ++k) {
    float w = W1[k * D + c];           // coalesced; L2-resident (64 KB)
#pragma unroll
    for (int r = 0; r < 8; ++r) acc[r] = fmaf(sE[rg + r][k], w, acc[r]);
  }
#pragma unroll
  for (int r = 0; r < 8; ++r) sO[rg + r][c] = acc[r];
  __syncthreads();
  for (int i = t; i < PR * 32; i += 256) {
    int r = i >> 5, li = i & 31;
    int v = row0 + r;
    if (v < V)
      P1p8[(size_t)v * 32 + li] =
          enc4_e5m2(sO[r][4 * li], sO[r][4 * li + 1], sO[r][4 * li + 2], sO[r][4 * li + 3]);
  }
}

// ---------- K2: bin histogram (bin = dst>>8), LDS-staged ----------
__global__ __launch_bounds__(512)
void k_hist(const int* __restrict__ dst, int* __restrict__ binCnt) {
  __shared__ int h[NBIN];
  int t = threadIdx.x;
  for (int i = t; i < NBIN; i += 512) h[i] = 0;
  __syncthreads();
  int base = blockIdx.x * EPB;
#pragma unroll
  for (int i = 0; i < EPB / 512; ++i) {
    int e = base + i * 512 + t;
    if (e < NE) atomicAdd(&h[dst[e] >> BSH], 1);
  }
  __syncthreads();
  for (int i = t; i < NBIN; i += 512)
    if (h[i]) atomicAdd(&binCnt[i], h[i]);
}

// ---------- K3: scan bins -> staging offsets + padded payload offsets ----------
// padded stride per bin rounded to x4 so all rowD / graph boundaries are x4.
// also writes rowD[NT] = total padded payload size (graph-49 end sentinel).
__global__ void k_binscan(const int* __restrict__ binCnt,
                          int* __restrict__ stageBase, int* __restrict__ payBase,
                          int* __restrict__ rowD) {
  __shared__ int s[512], p[512];
  int t = threadIdx.x;                     // 512 threads
  int c = (t < NBIN) ? binCnt[t] : 0;
  int cp = (t < NBIN) ? ((c + SLACK + 3) & ~3) : 0;
  s[t] = c; p[t] = cp;
  __syncthreads();
  for (int off = 1; off < 512; off <<= 1) {
    int a = (t >= off) ? s[t - off] : 0;
    int b = (t >= off) ? p[t - off] : 0;
    __syncthreads();
    s[t] += a; p[t] += b;
    __syncthreads();
  }
  if (t < NBIN) { stageBase[t] = s[t] - c; payBase[t] = p[t] - cp; }
  if (t == NBIN - 1) rowD[NT] = p[t];
}

// ---------- K4: bin-fill: LDS-group 4096 edges by bin, flush dense segments ----------
// record: .x = w_bf16<<16 | wid (14b) ; .y = src (17b) | dstLocal<<17 (8b)
__global__ __launch_bounds__(512)
void k_binfill(const int* __restrict__ src, const int* __restrict__ dst,
               const float* __restrict__ ew, const int* __restrict__ node_ids,
               const int* __restrict__ stageBase, int* __restrict__ binCursor,
               int2* __restrict__ stage) {
  __shared__ int h[512], sc[512], gbase[512], cur[512];
  __shared__ int2 buf[EPB];                 // 32 KB
  int t = threadIdx.x;
  h[t] = 0;
  __syncthreads();
  int base = blockIdx.x * EPB;
  int d_[EPB / 512], b_[EPB / 512];
#pragma unroll
  for (int i = 0; i < EPB / 512; ++i) {
    int e = base + i * 512 + t;
    int d = (e < NE) ? dst[e] : -1;
    d_[i] = d;
    b_[i] = (d >= 0) ? (d >> BSH) : -1;
    if (d >= 0) atomicAdd(&h[b_[i]], 1);
  }
  __syncthreads();
  int c = h[t];
  sc[t] = c;
  __syncthreads();
  for (int off = 1; off < 512; off <<= 1) {
    int a = (t >= off) ? sc[t - off] : 0;
    __syncthreads();
    sc[t] += a;
    __syncthreads();
  }
  cur[t] = sc[t] - c;                       // exclusive local offset
  if (t < NBIN && c > 0) gbase[t] = atomicAdd(&binCursor[t], c);
  __syncthreads();
#pragma unroll
  for (int i = 0; i < EPB / 512; ++i) {
    int e = base + i * 512 + t;
    if (e < NE) {
      int s = src[e];
      unsigned uw = __float_as_uint(ew[e]);
      unsigned wb = (uw + 0x7fffu + ((uw >> 16) & 1u)) & 0xffff0000u;  // RN bf16
      int wid = node_ids[s];
      int dl = d_[i] & (BIN_DSTS - 1);
      int p = atomicAdd(&cur[b_[i]], 1);
      buf[p] = make_int2((int)(wb | (unsigned)wid), s | (dl << 17));
    }
  }
  __syncthreads();
  for (int b = t; b < NBIN; b += 512) {     // flush contiguous per-bin segments
    int len = h[b];
    if (!len) continue;
    int gp = stageBase[b] + gbase[b];
    int lp = sc[b] - len;
    for (int k = 0; k < len; ++k) stage[gp + k] = buf[lp + k];
  }
}

// ---------- K5: per-bin LDS counting-sort -> padded per-dst CSR ----------
// Folds 1/deg into the stored weight: w' = bf16(w * (1/deg)).
__global__ __launch_bounds__(256)
void k_binsort(const int2* __restrict__ stage, const int* __restrict__ binCnt,
               const int* __restrict__ stageBase, const int* __restrict__ payBase,
               int* __restrict__ rowD, int* __restrict__ cntD,
               int2* __restrict__ pay) {
  __shared__ int h2[BIN_DSTS], ro[BIN_DSTS], cur2[BIN_DSTS];
  __shared__ float invD[BIN_DSTS];
  __shared__ int2 buf[BUF_SORT];            // 44 KB
  int b = blockIdx.x, t = threadIdx.x;
  int cnt = binCnt[b], sb = stageBase[b], pb = payBase[b];
  int dst0 = b << BSH;
  h2[t] = 0;
  __syncthreads();
  for (int i = t; i < cnt; i += 256)
    atomicAdd(&h2[(stage[sb + i].y >> 17) & 255], 1);
  __syncthreads();
  int c = h2[t];
  invD[t] = (c > 0) ? (1.0f / (float)c) : 0.0f;
  int pc = (c + 3) & ~3;                    // row padded to x4
  ro[t] = pc;
  __syncthreads();
  for (int off = 1; off < 256; off <<= 1) {
    int a = (t >= off) ? ro[t - off] : 0;
    __syncthreads();
    ro[t] += a;
    __syncthreads();
  }
  int myoff = ro[t] - pc;                   // exclusive padded offset
  int n = dst0 + t;
  if (n < NT) { rowD[n] = pb + myoff; cntD[n] = c; }
  cur2[t] = myoff;
  __syncthreads();
  int cpL = (cnt + SLACK + 3) & ~3;         // flush exactly tiles pay (no gaps)
  for (int i = t; i < cpL; i += 256) buf[i] = make_int2(0, 0);
  __syncthreads();
  for (int i = t; i < cnt; i += 256) {
    int2 r = stage[sb + i];
    int dl = (r.y >> 17) & 255;
    float w = __uint_as_float((unsigned)r.x & 0xffff0000u);
    float wp = w * invD[dl];
    unsigned uw = __float_as_uint(wp);
    unsigned wb2 = (uw + 0x7fffu + ((uw >> 16) & 1u)) & 0xffff0000u;
    int p = atomicAdd(&cur2[dl], 1);
    buf[p] = make_int2((int)(wb2 | ((unsigned)r.x & 0xffffu)), r.y & 0x1ffff);
  }
  __syncthreads();
  for (int i = t; i < cpL; i += 256) pay[pb + i] = buf[i];
}

// ---- shared row-gather: 4 edges/iter, BRANCH-FREE pipeline (unchanged) ----
template<bool USE_WID>
__device__ __forceinline__ int pick_idx(const int4& q, int half) {
  int lo = USE_WID ? (q.x & 0xffff) : q.y;
  int hi = USE_WID ? (q.z & 0xffff) : q.w;
  return half ? hi : lo;
}
__device__ __forceinline__ void consume2(const int4& q, unsigned v, int half,
                                         float& a0, float& a1, float& a2, float& a3,
                                         float& sw) {
  int wm = half ? q.z : q.x;
  float w = __uint_as_float((unsigned)wm & 0xffff0000u);
  float4 x = dec4_e5m2(v);
  a0 = fmaf(w, x.x, a0); a1 = fmaf(w, x.y, a1);
  a2 = fmaf(w, x.z, a2); a3 = fmaf(w, x.w, a3);
  sw += w;
}

template<bool USE_WID>
__device__ __forceinline__ void gather_row(const int2* __restrict__ pay,
                                           const unsigned* __restrict__ tab,
                                           int beg, int cnt, int li, int half,
                                           float& a0, float& a1, float& a2, float& a3,
                                           float& sw) {
  int G = (cnt + 3) >> 2;                       // groups of 4 edges (rows padded)
  const int4* __restrict__ pp = (const int4*)(pay + beg);
  int4 q0a = pp[0], q0b = pp[1];
  int4 q1a = pp[2], q1b = pp[3];
  int4 q2a = pp[4], q2b = pp[5];
  int4 q3a = pp[6], q3b = pp[7];
  int4 q4a = pp[8], q4b = pp[9];
  unsigned va0 = tab[(size_t)pick_idx<USE_WID>(q0a, half) * 32 + li];
  unsigned vb0 = tab[(size_t)pick_idx<USE_WID>(q0b, half) * 32 + li];
  unsigned va1 = tab[(size_t)pick_idx<USE_WID>(q1a, half) * 32 + li];
  unsigned vb1 = tab[(size_t)pick_idx<USE_WID>(q1b, half) * 32 + li];
  unsigned va2 = tab[(size_t)pick_idx<USE_WID>(q2a, half) * 32 + li];
  unsigned vb2 = tab[(size_t)pick_idx<USE_WID>(q2b, half) * 32 + li];
  for (int g = 0; g < G; ++g) {
    unsigned vn0 = tab[(size_t)pick_idx<USE_WID>(q3a, half) * 32 + li];
    unsigned vn1 = tab[(size_t)pick_idx<USE_WID>(q3b, half) * 32 + li];
    int4 qna = pp[2 * g + 10];
    int4 qnb = pp[2 * g + 11];
    consume2(q0a, va0, half, a0, a1, a2, a3, sw);
    consume2(q0b, vb0, half, a0, a1, a2, a3, sw);
    q0a = q1a; q0b = q1b; q1a = q2a; q1b = q2b; q2a = q3a; q2b = q3b;
    q3a = q4a; q3b = q4b; q4a = qna; q4b = qnb;
    va0 = va1; vb0 = vb1; va1 = va2; vb1 = vb2; va2 = vn0; vb2 = vn1;
  }
}

// ---------- K7: layer-1 aggregate (w' folded mean) + leaky -> h1p8 ----------
__global__ void k_agg1(const int2* __restrict__ pay,
                       const int* __restrict__ rowD, const int* __restrict__ cntD,
                       const unsigned* __restrict__ P1p8,
                       unsigned* __restrict__ h1p8) {
  int n = blockIdx.x * 4 + (threadIdx.x >> 6);
  int lane = threadIdx.x & 63;
  int li = lane & 31, half = lane >> 5;
  int beg = __builtin_amdgcn_readfirstlane(rowD[n]);
  int cnt = __builtin_amdgcn_readfirstlane(cntD[n]);
  float a0 = 0.f, a1 = 0.f, a2 = 0.f, a3 = 0.f, sw = 0.f;
  gather_row<true>(pay, P1p8, beg, cnt, li, half, a0, a1, a2, a3, sw);
  a0 += __shfl_down(a0, 32);
  a1 += __shfl_down(a1, 32);
  a2 += __shfl_down(a2, 32);
  a3 += __shfl_down(a3, 32);
  if (lane < 32) {
    float x0 = a0, x1 = a1, x2 = a2, x3 = a3;   // w'=w/deg -> already the mean
    x0 = (x0 > 0.f) ? x0 : 0.01f * x0;     // leaky_relu(0)=0 keeps deg==0 rows 0
    x1 = (x1 > 0.f) ? x1 : 0.01f * x1;
    x2 = (x2 > 0.f) ? x2 : 0.01f * x2;
    x3 = (x3 > 0.f) ? x3 : 0.01f * x3;
    h1p8[(size_t)n * 32 + li] = enc4_e5m2(x0, x1, x2, x3);
  }
}

// ---------- K8: layer-2 LINEAR edge scan fused with per-graph pooling ----------
// pool_g = sum_e w'_e * h1[src_e]; graph ranges are contiguous in pay.
__global__ void k_agg2(const int2* __restrict__ pay,
                       const int* __restrict__ rowD,
                       const unsigned* __restrict__ h1p8,
                       float* __restrict__ pool) {
  int g = blockIdx.x >> 5;                  // / A2_BPG
  int blk = blockIdx.x & (A2_BPG - 1);
  int w = threadIdx.x >> 6, lane = threadIdx.x & 63;
  int li = lane & 31, half = lane >> 5;
  int base = __builtin_amdgcn_readfirstlane(rowD[g * NODES_PER_GRAPH]);
  int end  = __builtin_amdgcn_readfirstlane(
      (g == B_GRAPHS - 1) ? rowD[NT] : rowD[(g + 1) * NODES_PER_GRAPH]);
  int groups = (end - base) >> 2;
  int gpw = (groups + 4 * A2_BPG - 1) / (4 * A2_BPG);
  int slot = blk * 4 + w;
  int g0 = slot * gpw;
  int myg = groups - g0;
  myg = (myg < 0) ? 0 : ((myg > gpw) ? gpw : myg);
  float s0 = 0.f, s1 = 0.f, s2 = 0.f, s3 = 0.f, sc = 0.f;
  gather_row<false>(pay, h1p8, base + g0 * 4, myg * 4, li, half, s0, s1, s2, s3, sc);
  s0 += __shfl_down(s0, 32);
  s1 += __shfl_down(s1, 32);
  s2 += __shfl_down(s2, 32);
  s3 += __shfl_down(s3, 32);
  sc += __shfl_down(sc, 32);
  __shared__ float sS[4 * 128];
  __shared__ float sC[4];
  if (lane < 32) {
    sS[w * 128 + 4 * li + 0] = s0;
    sS[w * 128 + 4 * li + 1] = s1;
    sS[w * 128 + 4 * li + 2] = s2;
    sS[w * 128 + 4 * li + 3] = s3;
  }
  if (lane == 0) sC[w] = sc;
  __syncthreads();
  int t = threadIdx.x;
  if (t < 128) {
    float v = sS[t] + sS[128 + t] + sS[256 + t] + sS[384 + t];
    atomicAdd(&pool[g * D + t], v);
  }
  if (t == 0) atomicAdd(&pool[B_GRAPHS * D + g], sC[0] + sC[1] + sC[2] + sC[3]);
}

// ---------- K9: head ----------
__global__ void k_final(const float* __restrict__ poolS, const float* __restrict__ poolC,
                        const float* __restrict__ W2, const float* __restrict__ b2,
                        const float* __restrict__ W_out, const float* __restrict__ b_out,
                        const float* __restrict__ y, float* __restrict__ out) {
  int t = threadIdx.x;  // 128 threads
  __shared__ float w2o[D];
  __shared__ float red[D];
  __shared__ float s2o_sh;
  __shared__ float logits[B_GRAPHS];
  float acc = 0.f;
  for (int d = 0; d < D; ++d) acc = fmaf(W2[t * D + d], W_out[d], acc);
  w2o[t] = acc;
  red[t] = b2[t] * W_out[t];
  __syncthreads();
  for (int off = 64; off > 0; off >>= 1) {
    if (t < off) red[t] += red[t + off];
    __syncthreads();
  }
  if (t == 0) s2o_sh = red[0];
  __syncthreads();
  float s2o = s2o_sh;
  float bout = b_out[0];
  const float invN = 1.0f / (float)NODES_PER_GRAPH;
  for (int g = 0; g < B_GRAPHS; ++g) {
    red[t] = poolS[g * D + t] * w2o[t];
    __syncthreads();
    for (int off = 64; off > 0; off >>= 1) {
      if (t < off) red[t] += red[t + off];
      __syncthreads();
    }
    if (t == 0) logits[g] = red[0] * invN + poolC[g] * invN * s2o + bout;
    __syncthreads();
  }
  float term = 0.f;
  if (t < B_GRAPHS) {
    float l = logits[t];
    out[1 + t] = 1.0f / (1.0f + expf(-l));            // y_pred
    term = fmaxf(l, 0.f) - l * y[t] + log1pf(expf(-fabsf(l)));
  }
  red[t] = term;
  __syncthreads();
  for (int off = 64; off > 0; off >>= 1) {
    if (t < off) red[t] += red[t + off];
    __syncthreads();
  }
  if (t == 0) out[0] = red[0] / (float)B_GRAPHS;      // loss
}

extern "C" void kernel_launch(void* const* d_in, const int* in_sizes, int n_in,
                              void* d_out, int out_size, void* d_ws, size_t ws_size,
                              hipStream_t stream) {
  const int*   node_ids = (const int*)d_in[0];
  const int*   src      = (const int*)d_in[1];
  const int*   dst      = (const int*)d_in[2];
  const float* ew       = (const float*)d_in[3];
  const float* y        = (const float*)d_in[4];
  const float* embeds   = (const float*)d_in[5];
  const float* W1       = (const float*)d_in[6];
  const float* b1       = (const float*)d_in[7];
  const float* W2       = (const float*)d_in[8];
  const float* b2       = (const float*)d_in[9];
  const float* W_out    = (const float*)d_in[10];
  const float* b_out    = (const float*)d_in[11];
  float* out = (float*)d_out;
  (void)in_sizes; (void)n_in; (void)out_size; (void)ws_size;

  char* ws = (char*)d_ws;
  size_t off = 0;
  auto alloc = [&](size_t bytes) {
    size_t r = off;
    off = (off + bytes + 511) & ~(size_t)511;
    return r;
  };
  // zero region (poisoned 0xAA before every call)
  size_t o_binCnt = alloc(512 * 4);
  size_t o_binCur = alloc(512 * 4);
  size_t o_pool   = alloc((size_t)POOL_N * 4);
  size_t zero_end = off;
  // non-zeroed
  size_t o_sBase  = alloc(512 * 4);
  size_t o_pBase  = alloc(512 * 4);
  size_t o_rowD   = alloc((size_t)(NT + 1) * 4);
  size_t o_cntD   = alloc((size_t)NT * 4);
  size_t o_P1p8   = alloc((size_t)V * 32 * 4);          // 1.92 MB
  size_t o_h1p8   = alloc((size_t)NT * 32 * 4);         // 12.8 MB
  size_t o_stage  = alloc((size_t)NE * 8);              // 12.8 MB
  size_t o_pay    = alloc((size_t)PAY_CAP2 * 8);        // 15.2 MB

  int*      binCnt   = (int*)(ws + o_binCnt);
  int*      binCursor= (int*)(ws + o_binCur);
  float*    pool     = (float*)(ws + o_pool);
  int*      stageBase= (int*)(ws + o_sBase);
  int*      payBase  = (int*)(ws + o_pBase);
  int*      rowD     = (int*)(ws + o_rowD);
  int*      cntD     = (int*)(ws + o_cntD);
  unsigned* P1p8     = (unsigned*)(ws + o_P1p8);
  unsigned* h1p8     = (unsigned*)(ws + o_h1p8);
  int2*     stage    = (int2*)(ws + o_stage);
  int2*     pay      = (int2*)(ws + o_pay);

  hipMemsetAsync(ws, 0, zero_end, stream);
  // zero the pay tail (prologue overrun past rowD[NT] reads into it)
  hipMemsetAsync(pay + (PAY_CAP2 - 512), 0, 512 * 8, stream);

  k_project<<<(V + PR - 1) / PR, 256, 0, stream>>>(embeds, W1, b1, P1p8);
  k_hist<<<NFB, 512, 0, stream>>>(dst, binCnt);
  k_binscan<<<1, 512, 0, stream>>>(binCnt, stageBase, payBase, rowD);
  k_binfill<<<NFB, 512, 0, stream>>>(src, dst, ew, node_ids,
                                     stageBase, binCursor, stage);
  k_binsort<<<NBIN, 256, 0, stream>>>(stage, binCnt, stageBase, payBase,
                                      rowD, cntD, pay);
  k_agg1<<<NT / 4, 256, 0, stream>>>(pay, rowD, cntD, P1p8, h1p8);
  k_agg2<<<B_GRAPHS * A2_BPG, 256, 0, stream>>>(pay, rowD, h1p8, pool);
  k_final<<<1, 128, 0, stream>>>(pool, pool + B_GRAPHS * D, W2, b2, W_out, b_out, y, out);
}

// Round 11
// 309.225 us; speedup vs baseline: 1.0057x; 1.0057x over previous
//
#include <hip/hip_runtime.h>
#include <hip/hip_fp16.h>
#include <math.h>

#define NT 100000
#define B_GRAPHS 50
#define NE 1600000
#define V 15000
#define D 128
#define NODES_PER_GRAPH (NT / B_GRAPHS)   // 2000

#define POOL_N (B_GRAPHS * D + B_GRAPHS)  // 6450

#define BSH 8
#define BIN_DSTS 256
#define NBIN ((NT + BIN_DSTS - 1) / BIN_DSTS)   // 391
#define SLACK (3 * BIN_DSTS)                    // 768 (worst-case row padding)
#define EPB 4096                                // edges per k_binfill block
#define NFB ((NE + EPB - 1) / EPB)              // 391
#define BUF_SORT 5632                           // per-bin LDS record cap
#define PAY_CAP2 (NE + NBIN * (SLACK + 4) + 512)

// ---- e5m2 helpers: code = top byte of fp16 (RN). decode = byte<<8 as half ----
__device__ __forceinline__ unsigned enc2_e5m2(float a, float b) {
  unsigned ha = __half_as_ushort(__float2half(a));
  unsigned hb = __half_as_ushort(__float2half(b));
  ha = ((ha + 0x7fu + ((ha >> 8) & 1u)) >> 8) & 0xffu;
  hb = ((hb + 0x7fu + ((hb >> 8) & 1u)) >> 8) & 0xffu;
  return ha | (hb << 8);
}
__device__ __forceinline__ unsigned enc4_e5m2(float a, float b, float c, float d) {
  return enc2_e5m2(a, b) | (enc2_e5m2(c, d) << 16);
}
__device__ __forceinline__ float4 dec4_e5m2(unsigned u) {
  unsigned hp0 = ((u & 0xffu) << 8) | ((u & 0xff00u) << 16);      // dims d, d+1
  unsigned hp1 = ((u >> 8) & 0xff00u) | (u & 0xff000000u);        // dims d+2, d+3
  __half2 h0 = *(__half2*)&hp0;
  __half2 h1 = *(__half2*)&hp1;
  float2 f0 = __half22float2(h0);
  float2 f1 = __half22float2(h1);
  return make_float4(f0.x, f0.y, f1.x, f1.y);
}

// ---------- K1: P1p8 = e5m2(embeds @ W1 + b1)  [V, 32 uints] ----------
#define PR 16
__global__ __launch_bounds__(256, 8)
void k_project(const float* __restrict__ embeds,
               const float* __restrict__ W1,
               const float* __restrict__ b1,
               unsigned* __restrict__ P1p8) {
  __shared__ float sE[PR][D];          // 8 KB
  __shared__ float sO[PR][D];          // 8 KB
  int t = threadIdx.x;
  int row0 = blockIdx.x * PR;
  for (int i = t; i < PR * D; i += 256) {
    int r = i >> 7, c = i & 127;
    int v = row0 + r;
    sE[r][c] = (v < V) ? embeds[(size_t)v * D + c] : 0.f;
  }
  __syncthreads();
  int c = t & 127, rg = (t >> 7) * 8;  // this thread: col c, rows rg..rg+7
  float bd = b1[c];
  float acc[8];
#pragma unroll
  for (int r = 0; r < 8; ++r) acc[r] = bd;
#pragma unroll 4
  for (int k = 0; k < D; ++k) {
    float w = W1[k * D + c];           // coalesced; L2-resident (64 KB)
#pragma unroll
    for (int r = 0; r < 8; ++r) acc[r] = fmaf(sE[rg + r][k], w, acc[r]);
  }
#pragma unroll
  for (int r = 0; r < 8; ++r) sO[rg + r][c] = acc[r];
  __syncthreads();
  for (int i = t; i < PR * 32; i += 256) {
    int r = i >> 5, li = i & 31;
    int v = row0 + r;
    if (v < V)
      P1p8[(size_t)v * 32 + li] =
          enc4_e5m2(sO[r][4 * li], sO[r][4 * li + 1], sO[r][4 * li + 2], sO[r][4 * li + 3]);
  }
}

// ---------- K2: bin histogram (bin = dst>>8), LDS-staged ----------
__global__ __launch_bounds__(512)
void k_hist(const int* __restrict__ dst, int* __restrict__ binCnt) {
  __shared__ int h[NBIN];
  int t = threadIdx.x;
  for (int i = t; i < NBIN; i += 512) h[i] = 0;
  __syncthreads();
  int base = blockIdx.x * EPB;
#pragma unroll
  for (int i = 0; i < EPB / 512; ++i) {
    int e = base + i * 512 + t;
    if (e < NE) atomicAdd(&h[dst[e] >> BSH], 1);
  }
  __syncthreads();
  for (int i = t; i < NBIN; i += 512)
    if (h[i]) atomicAdd(&binCnt[i], h[i]);
}

// ---------- K3: scan bins -> staging offsets + padded payload offsets ----------
__global__ void k_binscan(const int* __restrict__ binCnt,
                          int* __restrict__ stageBase, int* __restrict__ payBase,
                          int* __restrict__ rowD) {
  __shared__ int s[512], p[512];
  int t = threadIdx.x;                     // 512 threads
  int c = (t < NBIN) ? binCnt[t] : 0;
  int cp = (t < NBIN) ? ((c + SLACK + 3) & ~3) : 0;
  s[t] = c; p[t] = cp;
  __syncthreads();
  for (int off = 1; off < 512; off <<= 1) {
    int a = (t >= off) ? s[t - off] : 0;
    int b = (t >= off) ? p[t - off] : 0;
    __syncthreads();
    s[t] += a; p[t] += b;
    __syncthreads();
  }
  if (t < NBIN) { stageBase[t] = s[t] - c; payBase[t] = p[t] - cp; }
  if (t == NBIN - 1) rowD[NT] = p[t];
}

// ---------- K4: bin-fill: LDS-group 4096 edges by bin, flush dense segments ----------
// record: .x = w_bf16<<16 | wid (14b) ; .y = src (17b) | dstLocal<<17 (8b)
__global__ __launch_bounds__(512)
void k_binfill(const int* __restrict__ src, const int* __restrict__ dst,
               const float* __restrict__ ew, const int* __restrict__ node_ids,
               const int* __restrict__ stageBase, int* __restrict__ binCursor,
               int2* __restrict__ stage) {
  __shared__ int h[512], sc[512], gbase[512], cur[512];
  __shared__ int2 buf[EPB];                 // 32 KB
  int t = threadIdx.x;
  h[t] = 0;
  __syncthreads();
  int base = blockIdx.x * EPB;
  int d_[EPB / 512], b_[EPB / 512];
#pragma unroll
  for (int i = 0; i < EPB / 512; ++i) {
    int e = base + i * 512 + t;
    int d = (e < NE) ? dst[e] : -1;
    d_[i] = d;
    b_[i] = (d >= 0) ? (d >> BSH) : -1;
    if (d >= 0) atomicAdd(&h[b_[i]], 1);
  }
  __syncthreads();
  int c = h[t];
  sc[t] = c;
  __syncthreads();
  for (int off = 1; off < 512; off <<= 1) {
    int a = (t >= off) ? sc[t - off] : 0;
    __syncthreads();
    sc[t] += a;
    __syncthreads();
  }
  cur[t] = sc[t] - c;                       // exclusive local offset
  if (t < NBIN && c > 0) gbase[t] = atomicAdd(&binCursor[t], c);
  __syncthreads();
#pragma unroll
  for (int i = 0; i < EPB / 512; ++i) {
    int e = base + i * 512 + t;
    if (e < NE) {
      int s = src[e];
      unsigned uw = __float_as_uint(ew[e]);
      unsigned wb = (uw + 0x7fffu + ((uw >> 16) & 1u)) & 0xffff0000u;  // RN bf16
      int wid = node_ids[s];
      int dl = d_[i] & (BIN_DSTS - 1);
      int p = atomicAdd(&cur[b_[i]], 1);
      buf[p] = make_int2((int)(wb | (unsigned)wid), s | (dl << 17));
    }
  }
  __syncthreads();
  for (int b = t; b < NBIN; b += 512) {     // flush contiguous per-bin segments
    int len = h[b];
    if (!len) continue;
    int gp = stageBase[b] + gbase[b];
    int lp = sc[b] - len;
    for (int k = 0; k < len; ++k) stage[gp + k] = buf[lp + k];
  }
}

// ---------- K5: per-bin LDS counting-sort -> padded per-dst CSR ----------
// Folds 1/deg into the stored weight: w' = bf16(w * (1/deg)).
__global__ __launch_bounds__(256)
void k_binsort(const int2* __restrict__ stage, const int* __restrict__ binCnt,
               const int* __restrict__ stageBase, const int* __restrict__ payBase,
               int* __restrict__ rowD, int* __restrict__ cntD,
               int2* __restrict__ pay) {
  __shared__ int h2[BIN_DSTS], ro[BIN_DSTS], cur2[BIN_DSTS];
  __shared__ float invD[BIN_DSTS];
  __shared__ int2 buf[BUF_SORT];            // 44 KB
  int b = blockIdx.x, t = threadIdx.x;
  int cnt = binCnt[b], sb = stageBase[b], pb = payBase[b];
  int dst0 = b << BSH;
  h2[t] = 0;
  __syncthreads();
  for (int i = t; i < cnt; i += 256)
    atomicAdd(&h2[(stage[sb + i].y >> 17) & 255], 1);
  __syncthreads();
  int c = h2[t];
  invD[t] = (c > 0) ? (1.0f / (float)c) : 0.0f;
  int pc = (c + 3) & ~3;                    // row padded to x4
  ro[t] = pc;
  __syncthreads();
  for (int off = 1; off < 256; off <<= 1) {
    int a = (t >= off) ? ro[t - off] : 0;
    __syncthreads();
    ro[t] += a;
    __syncthreads();
  }
  int myoff = ro[t] - pc;                   // exclusive padded offset
  int n = dst0 + t;
  if (n < NT) { rowD[n] = pb + myoff; cntD[n] = c; }
  cur2[t] = myoff;
  __syncthreads();
  int cpL = (cnt + SLACK + 3) & ~3;         // flush exactly tiles pay (no gaps)
  for (int i = t; i < cpL; i += 256) buf[i] = make_int2(0, 0);
  __syncthreads();
  for (int i = t; i < cnt; i += 256) {
    int2 r = stage[sb + i];
    int dl = (r.y >> 17) & 255;
    float w = __uint_as_float((unsigned)r.x & 0xffff0000u);
    float wp = w * invD[dl];
    unsigned uw = __float_as_uint(wp);
    unsigned wb2 = (uw + 0x7fffu + ((uw >> 16) & 1u)) & 0xffff0000u;
    int p = atomicAdd(&cur2[dl], 1);
    buf[p] = make_int2((int)(wb2 | ((unsigned)r.x & 0xffffu)), r.y & 0x1ffff);
  }
  __syncthreads();
  for (int i = t; i < cpL; i += 256) pay[pb + i] = buf[i];
}

// ---- shared row-gather: 4 edges/iter, BRANCH-FREE pipeline (unchanged) ----
template<bool USE_WID>
__device__ __forceinline__ int pick_idx(const int4& q, int half) {
  int lo = USE_WID ? (q.x & 0xffff) : q.y;
  int hi = USE_WID ? (q.z & 0xffff) : q.w;
  return half ? hi : lo;
}
__device__ __forceinline__ void consume2(const int4& q, unsigned v, int half,
                                         float& a0, float& a1, float& a2, float& a3,
                                         float& sw) {
  int wm = half ? q.z : q.x;
  float w = __uint_as_float((unsigned)wm & 0xffff0000u);
  float4 x = dec4_e5m2(v);
  a0 = fmaf(w, x.x, a0); a1 = fmaf(w, x.y, a1);
  a2 = fmaf(w, x.z, a2); a3 = fmaf(w, x.w, a3);
  sw += w;
}

template<bool USE_WID>
__device__ __forceinline__ void gather_row(const int2* __restrict__ pay,
                                           const unsigned* __restrict__ tab,
                                           int beg, int cnt, int li, int half,
                                           float& a0, float& a1, float& a2, float& a3,
                                           float& sw) {
  int G = (cnt + 3) >> 2;                       // groups of 4 edges (rows padded)
  const int4* __restrict__ pp = (const int4*)(pay + beg);
  int4 q0a = pp[0], q0b = pp[1];
  int4 q1a = pp[2], q1b = pp[3];
  int4 q2a = pp[4], q2b = pp[5];
  int4 q3a = pp[6], q3b = pp[7];
  int4 q4a = pp[8], q4b = pp[9];
  unsigned va0 = tab[(size_t)pick_idx<USE_WID>(q0a, half) * 32 + li];
  unsigned vb0 = tab[(size_t)pick_idx<USE_WID>(q0b, half) * 32 + li];
  unsigned va1 = tab[(size_t)pick_idx<USE_WID>(q1a, half) * 32 + li];
  unsigned vb1 = tab[(size_t)pick_idx<USE_WID>(q1b, half) * 32 + li];
  unsigned va2 = tab[(size_t)pick_idx<USE_WID>(q2a, half) * 32 + li];
  unsigned vb2 = tab[(size_t)pick_idx<USE_WID>(q2b, half) * 32 + li];
  for (int g = 0; g < G; ++g) {
    unsigned vn0 = tab[(size_t)pick_idx<USE_WID>(q3a, half) * 32 + li];
    unsigned vn1 = tab[(size_t)pick_idx<USE_WID>(q3b, half) * 32 + li];
    int4 qna = pp[2 * g + 10];
    int4 qnb = pp[2 * g + 11];
    consume2(q0a, va0, half, a0, a1, a2, a3, sw);
    consume2(q0b, vb0, half, a0, a1, a2, a3, sw);
    q0a = q1a; q0b = q1b; q1a = q2a; q1b = q2b; q2a = q3a; q2b = q3b;
    q3a = q4a; q3b = q4b; q4a = qna; q4b = qnb;
    va0 = va1; vb0 = vb1; va1 = va2; vb1 = vb2; va2 = vn0; vb2 = vn1;
  }
}

// ---------- K7: layer-1 aggregate (w' folded mean) + leaky -> h1p8 ----------
__global__ void k_agg1(const int2* __restrict__ pay,
                       const int* __restrict__ rowD, const int* __restrict__ cntD,
                       const unsigned* __restrict__ P1p8,
                       unsigned* __restrict__ h1p8) {
  int n = blockIdx.x * 4 + (threadIdx.x >> 6);
  int lane = threadIdx.x & 63;
  int li = lane & 31, half = lane >> 5;
  int beg = __builtin_amdgcn_readfirstlane(rowD[n]);
  int cnt = __builtin_amdgcn_readfirstlane(cntD[n]);
  float a0 = 0.f, a1 = 0.f, a2 = 0.f, a3 = 0.f, sw = 0.f;
  gather_row<true>(pay, P1p8, beg, cnt, li, half, a0, a1, a2, a3, sw);
  a0 += __shfl_down(a0, 32);
  a1 += __shfl_down(a1, 32);
  a2 += __shfl_down(a2, 32);
  a3 += __shfl_down(a3, 32);
  if (lane < 32) {
    float x0 = a0, x1 = a1, x2 = a2, x3 = a3;   // w'=w/deg -> already the mean
    x0 = (x0 > 0.f) ? x0 : 0.01f * x0;     // leaky_relu(0)=0 keeps deg==0 rows 0
    x1 = (x1 > 0.f) ? x1 : 0.01f * x1;
    x2 = (x2 > 0.f) ? x2 : 0.01f * x2;
    x3 = (x3 > 0.f) ? x3 : 0.01f * x3;
    h1p8[(size_t)n * 32 + li] = enc4_e5m2(x0, x1, x2, x3);
  }
}

// ---------- K8: layer-2 per-node gather fused with per-graph pooling ----------
// R9 shape (proven 61 us @10k waves) at 2x parallelism: NPW2=5 -> 20k waves.
// w' folded: accumulators run straight through nodes, no inv, no cnt branch.
#define NPW2 5
#define BLKS_PER_G (NODES_PER_GRAPH / (4 * NPW2))   // 100
__global__ void k_agg2(const int2* __restrict__ pay,
                       const int* __restrict__ rowD, const int* __restrict__ cntD,
                       const unsigned* __restrict__ h1p8,
                       float* __restrict__ pool) {
  int g = blockIdx.x / BLKS_PER_G;
  int chunk = blockIdx.x % BLKS_PER_G;
  int w = threadIdx.x >> 6, lane = threadIdx.x & 63;
  int li = lane & 31, half = lane >> 5;
  int nbase = g * NODES_PER_GRAPH + chunk * (4 * NPW2) + w * NPW2;
  float s0 = 0.f, s1 = 0.f, s2 = 0.f, s3 = 0.f, sc = 0.f;
  for (int i = 0; i < NPW2; ++i) {
    int n = nbase + i;
    int beg = __builtin_amdgcn_readfirstlane(rowD[n]);
    int cnt = __builtin_amdgcn_readfirstlane(cntD[n]);
    gather_row<false>(pay, h1p8, beg, cnt, li, half, s0, s1, s2, s3, sc);
  }
  s0 += __shfl_down(s0, 32);
  s1 += __shfl_down(s1, 32);
  s2 += __shfl_down(s2, 32);
  s3 += __shfl_down(s3, 32);
  sc += __shfl_down(sc, 32);
  __shared__ float sS[4 * 128];
  __shared__ float sC[4];
  if (lane < 32) {
    sS[w * 128 + 4 * li + 0] = s0;
    sS[w * 128 + 4 * li + 1] = s1;
    sS[w * 128 + 4 * li + 2] = s2;
    sS[w * 128 + 4 * li + 3] = s3;
  }
  if (lane == 0) sC[w] = sc;
  __syncthreads();
  int t = threadIdx.x;
  if (t < 128) {
    float v = sS[t] + sS[128 + t] + sS[256 + t] + sS[384 + t];
    atomicAdd(&pool[g * D + t], v);
  }
  if (t == 0) atomicAdd(&pool[B_GRAPHS * D + g], sC[0] + sC[1] + sC[2] + sC[3]);
}

// ---------- K9: head ----------
__global__ void k_final(const float* __restrict__ poolS, const float* __restrict__ poolC,
                        const float* __restrict__ W2, const float* __restrict__ b2,
                        const float* __restrict__ W_out, const float* __restrict__ b_out,
                        const float* __restrict__ y, float* __restrict__ out) {
  int t = threadIdx.x;  // 128 threads
  __shared__ float w2o[D];
  __shared__ float red[D];
  __shared__ float s2o_sh;
  __shared__ float logits[B_GRAPHS];
  float acc = 0.f;
  for (int d = 0; d < D; ++d) acc = fmaf(W2[t * D + d], W_out[d], acc);
  w2o[t] = acc;
  red[t] = b2[t] * W_out[t];
  __syncthreads();
  for (int off = 64; off > 0; off >>= 1) {
    if (t < off) red[t] += red[t + off];
    __syncthreads();
  }
  if (t == 0) s2o_sh = red[0];
  __syncthreads();
  float s2o = s2o_sh;
  float bout = b_out[0];
  const float invN = 1.0f / (float)NODES_PER_GRAPH;
  for (int g = 0; g < B_GRAPHS; ++g) {
    red[t] = poolS[g * D + t] * w2o[t];
    __syncthreads();
    for (int off = 64; off > 0; off >>= 1) {
      if (t < off) red[t] += red[t + off];
      __syncthreads();
    }
    if (t == 0) logits[g] = red[0] * invN + poolC[g] * invN * s2o + bout;
    __syncthreads();
  }
  float term = 0.f;
  if (t < B_GRAPHS) {
    float l = logits[t];
    out[1 + t] = 1.0f / (1.0f + expf(-l));            // y_pred
    term = fmaxf(l, 0.f) - l * y[t] + log1pf(expf(-fabsf(l)));
  }
  red[t] = term;
  __syncthreads();
  for (int off = 64; off > 0; off >>= 1) {
    if (t < off) red[t] += red[t + off];
    __syncthreads();
  }
  if (t == 0) out[0] = red[0] / (float)B_GRAPHS;      // loss
}

extern "C" void kernel_launch(void* const* d_in, const int* in_sizes, int n_in,
                              void* d_out, int out_size, void* d_ws, size_t ws_size,
                              hipStream_t stream) {
  const int*   node_ids = (const int*)d_in[0];
  const int*   src      = (const int*)d_in[1];
  const int*   dst      = (const int*)d_in[2];
  const float* ew       = (const float*)d_in[3];
  const float* y        = (const float*)d_in[4];
  const float* embeds   = (const float*)d_in[5];
  const float* W1       = (const float*)d_in[6];
  const float* b1       = (const float*)d_in[7];
  const float* W2       = (const float*)d_in[8];
  const float* b2       = (const float*)d_in[9];
  const float* W_out    = (const float*)d_in[10];
  const float* b_out    = (const float*)d_in[11];
  float* out = (float*)d_out;
  (void)in_sizes; (void)n_in; (void)out_size; (void)ws_size;

  char* ws = (char*)d_ws;
  size_t off = 0;
  auto alloc = [&](size_t bytes) {
    size_t r = off;
    off = (off + bytes + 511) & ~(size_t)511;
    return r;
  };
  // zero region (poisoned 0xAA before every call)
  size_t o_binCnt = alloc(512 * 4);
  size_t o_binCur = alloc(512 * 4);
  size_t o_pool   = alloc((size_t)POOL_N * 4);
  size_t zero_end = off;
  // non-zeroed
  size_t o_sBase  = alloc(512 * 4);
  size_t o_pBase  = alloc(512 * 4);
  size_t o_rowD   = alloc((size_t)(NT + 1) * 4);
  size_t o_cntD   = alloc((size_t)NT * 4);
  size_t o_P1p8   = alloc((size_t)V * 32 * 4);          // 1.92 MB
  size_t o_h1p8   = alloc((size_t)NT * 32 * 4);         // 12.8 MB
  size_t o_stage  = alloc((size_t)NE * 8);              // 12.8 MB
  size_t o_pay    = alloc((size_t)PAY_CAP2 * 8);        // 15.2 MB

  int*      binCnt   = (int*)(ws + o_binCnt);
  int*      binCursor= (int*)(ws + o_binCur);
  float*    pool     = (float*)(ws + o_pool);
  int*      stageBase= (int*)(ws + o_sBase);
  int*      payBase  = (int*)(ws + o_pBase);
  int*      rowD     = (int*)(ws + o_rowD);
  int*      cntD     = (int*)(ws + o_cntD);
  unsigned* P1p8     = (unsigned*)(ws + o_P1p8);
  unsigned* h1p8     = (unsigned*)(ws + o_h1p8);
  int2*     stage    = (int2*)(ws + o_stage);
  int2*     pay      = (int2*)(ws + o_pay);

  hipMemsetAsync(ws, 0, zero_end, stream);
  // zero the pay tail (prologue overrun past rowD[NT] reads into it)
  hipMemsetAsync(pay + (PAY_CAP2 - 512), 0, 512 * 8, stream);

  k_project<<<(V + PR - 1) / PR, 256, 0, stream>>>(embeds, W1, b1, P1p8);
  k_hist<<<NFB, 512, 0, stream>>>(dst, binCnt);
  k_binscan<<<1, 512, 0, stream>>>(binCnt, stageBase, payBase, rowD);
  k_binfill<<<NFB, 512, 0, stream>>>(src, dst, ew, node_ids,
                                     stageBase, binCursor, stage);
  k_binsort<<<NBIN, 256, 0, stream>>>(stage, binCnt, stageBase, payBase,
                                      rowD, cntD, pay);
  k_agg1<<<NT / 4, 256, 0, stream>>>(pay, rowD, cntD, P1p8, h1p8);
  k_agg2<<<B_GRAPHS * BLKS_PER_G, 256, 0, stream>>>(pay, rowD, cntD, h1p8, pool);
  k_final<<<1, 128, 0, stream>>>(pool, pool + B_GRAPHS * D, W2, b2, W_out, b_out, y, out);
}

// Round 12
// 297.126 us; speedup vs baseline: 1.0466x; 1.0407x over previous
//
#include <hip/hip_runtime.h>
#include <hip/hip_fp16.h>
#include <math.h>

#define NT 100000
#define B_GRAPHS 50
#define NE 1600000
#define V 15000
#define D 128
#define NODES_PER_GRAPH (NT / B_GRAPHS)   // 2000

#define POOL_N (B_GRAPHS * D + B_GRAPHS)  // 6450

#define BSH 8
#define BIN_DSTS 256
#define NBIN ((NT + BIN_DSTS - 1) / BIN_DSTS)   // 391
#define SLACK (3 * BIN_DSTS)                    // 768 (worst-case row padding)
#define EPB 4096                                // edges per k_binfill block
#define NFB ((NE + EPB - 1) / EPB)              // 391
#define BUF_SORT 5632                           // per-bin LDS record cap
#define PAY_CAP2 (NE + NBIN * (SLACK + 4) + 512)

// ---- e5m2 helpers: code = top byte of fp16 (RN). decode = byte<<8 as half ----
__device__ __forceinline__ unsigned enc2_e5m2(float a, float b) {
  unsigned ha = __half_as_ushort(__float2half(a));
  unsigned hb = __half_as_ushort(__float2half(b));
  ha = ((ha + 0x7fu + ((ha >> 8) & 1u)) >> 8) & 0xffu;
  hb = ((hb + 0x7fu + ((hb >> 8) & 1u)) >> 8) & 0xffu;
  return ha | (hb << 8);
}
__device__ __forceinline__ unsigned enc4_e5m2(float a, float b, float c, float d) {
  return enc2_e5m2(a, b) | (enc2_e5m2(c, d) << 16);
}
__device__ __forceinline__ float4 dec4_e5m2(unsigned u) {
  unsigned hp0 = ((u & 0xffu) << 8) | ((u & 0xff00u) << 16);      // dims d, d+1
  unsigned hp1 = ((u >> 8) & 0xff00u) | (u & 0xff000000u);        // dims d+2, d+3
  __half2 h0 = *(__half2*)&hp0;
  __half2 h1 = *(__half2*)&hp1;
  float2 f0 = __half22float2(h0);
  float2 f1 = __half22float2(h1);
  return make_float4(f0.x, f0.y, f1.x, f1.y);
}

// ---------- K1: P1p8 = e5m2(embeds @ W1 + b1)  [V, 32 uints] ----------
#define PR 16
__global__ __launch_bounds__(256, 8)
void k_project(const float* __restrict__ embeds,
               const float* __restrict__ W1,
               const float* __restrict__ b1,
               unsigned* __restrict__ P1p8) {
  __shared__ float sE[PR][D];          // 8 KB
  __shared__ float sO[PR][D];          // 8 KB
  int t = threadIdx.x;
  int row0 = blockIdx.x * PR;
  for (int i = t; i < PR * D; i += 256) {
    int r = i >> 7, c = i & 127;
    int v = row0 + r;
    sE[r][c] = (v < V) ? embeds[(size_t)v * D + c] : 0.f;
  }
  __syncthreads();
  int c = t & 127, rg = (t >> 7) * 8;  // this thread: col c, rows rg..rg+7
  float bd = b1[c];
  float acc[8];
#pragma unroll
  for (int r = 0; r < 8; ++r) acc[r] = bd;
#pragma unroll 4
  for (int k = 0; k < D; ++k) {
    float w = W1[k * D + c];           // coalesced; L2-resident (64 KB)
#pragma unroll
    for (int r = 0; r < 8; ++r) acc[r] = fmaf(sE[rg + r][k], w, acc[r]);
  }
#pragma unroll
  for (int r = 0; r < 8; ++r) sO[rg + r][c] = acc[r];
  __syncthreads();
  for (int i = t; i < PR * 32; i += 256) {
    int r = i >> 5, li = i & 31;
    int v = row0 + r;
    if (v < V)
      P1p8[(size_t)v * 32 + li] =
          enc4_e5m2(sO[r][4 * li], sO[r][4 * li + 1], sO[r][4 * li + 2], sO[r][4 * li + 3]);
  }
}

// ---------- K2: bin histogram (bin = dst>>8), LDS-staged ----------
__global__ __launch_bounds__(512)
void k_hist(const int* __restrict__ dst, int* __restrict__ binCnt) {
  __shared__ int h[NBIN];
  int t = threadIdx.x;
  for (int i = t; i < NBIN; i += 512) h[i] = 0;
  __syncthreads();
  int base = blockIdx.x * EPB;
#pragma unroll
  for (int i = 0; i < EPB / 512; ++i) {
    int e = base + i * 512 + t;
    if (e < NE) atomicAdd(&h[dst[e] >> BSH], 1);
  }
  __syncthreads();
  for (int i = t; i < NBIN; i += 512)
    if (h[i]) atomicAdd(&binCnt[i], h[i]);
}

// ---------- K3: scan bins -> staging offsets + padded payload offsets ----------
__global__ void k_binscan(const int* __restrict__ binCnt,
                          int* __restrict__ stageBase, int* __restrict__ payBase,
                          int* __restrict__ rowD) {
  __shared__ int s[512], p[512];
  int t = threadIdx.x;                     // 512 threads
  int c = (t < NBIN) ? binCnt[t] : 0;
  int cp = (t < NBIN) ? ((c + SLACK + 3) & ~3) : 0;
  s[t] = c; p[t] = cp;
  __syncthreads();
  for (int off = 1; off < 512; off <<= 1) {
    int a = (t >= off) ? s[t - off] : 0;
    int b = (t >= off) ? p[t - off] : 0;
    __syncthreads();
    s[t] += a; p[t] += b;
    __syncthreads();
  }
  if (t < NBIN) { stageBase[t] = s[t] - c; payBase[t] = p[t] - cp; }
  if (t == NBIN - 1) rowD[NT] = p[t];
}

// ---------- K4: bin-fill: LDS-group 4096 edges by bin, flush dense segments ----------
// record: .x = w_bf16<<16 | wid (14b) ; .y = src (17b) | dstLocal<<17 (8b)
// flush is record-parallel (coalesced within segments), via binOf[] lookup.
__global__ __launch_bounds__(512)
void k_binfill(const int* __restrict__ src, const int* __restrict__ dst,
               const float* __restrict__ ew, const int* __restrict__ node_ids,
               const int* __restrict__ stageBase, int* __restrict__ binCursor,
               int2* __restrict__ stage) {
  __shared__ int h[512], sc[512], gbase[512], cur[512];
  __shared__ unsigned short binOf[EPB];     // 8 KB
  __shared__ int2 buf[EPB];                 // 32 KB
  int t = threadIdx.x;
  h[t] = 0;
  __syncthreads();
  int base = blockIdx.x * EPB;
  int d_[EPB / 512], b_[EPB / 512];
#pragma unroll
  for (int i = 0; i < EPB / 512; ++i) {
    int e = base + i * 512 + t;
    int d = (e < NE) ? dst[e] : -1;
    d_[i] = d;
    b_[i] = (d >= 0) ? (d >> BSH) : -1;
    if (d >= 0) atomicAdd(&h[b_[i]], 1);
  }
  __syncthreads();
  int c = h[t];
  sc[t] = c;
  __syncthreads();
  for (int off = 1; off < 512; off <<= 1) {
    int a = (t >= off) ? sc[t - off] : 0;
    __syncthreads();
    sc[t] += a;
    __syncthreads();
  }
  cur[t] = sc[t] - c;                       // exclusive local offset
  if (t < NBIN && c > 0) gbase[t] = atomicAdd(&binCursor[t], c);
  __syncthreads();
  int total = sc[511];                      // valid records in buf
#pragma unroll
  for (int i = 0; i < EPB / 512; ++i) {
    int e = base + i * 512 + t;
    if (e < NE) {
      int s = src[e];
      unsigned uw = __float_as_uint(ew[e]);
      unsigned wb = (uw + 0x7fffu + ((uw >> 16) & 1u)) & 0xffff0000u;  // RN bf16
      int wid = node_ids[s];
      int dl = d_[i] & (BIN_DSTS - 1);
      int p = atomicAdd(&cur[b_[i]], 1);
      buf[p] = make_int2((int)(wb | (unsigned)wid), s | (dl << 17));
      binOf[p] = (unsigned short)b_[i];
    }
  }
  __syncthreads();
  for (int i = t; i < total; i += 512) {    // record-parallel coalesced flush
    int b = binOf[i];
    int local = i - (sc[b] - h[b]);         // offset within this block's segment
    stage[stageBase[b] + gbase[b] + local] = buf[i];
  }
}

// ---------- K5: per-bin LDS counting-sort -> padded per-dst CSR ----------
// Folds 1/deg into the stored weight: w' = bf16(w * (1/deg)).
__global__ __launch_bounds__(256)
void k_binsort(const int2* __restrict__ stage, const int* __restrict__ binCnt,
               const int* __restrict__ stageBase, const int* __restrict__ payBase,
               int* __restrict__ rowD, int* __restrict__ cntD,
               int2* __restrict__ pay) {
  __shared__ int h2[BIN_DSTS], ro[BIN_DSTS], cur2[BIN_DSTS];
  __shared__ float invD[BIN_DSTS];
  __shared__ int2 buf[BUF_SORT];            // 44 KB
  int b = blockIdx.x, t = threadIdx.x;
  int cnt = binCnt[b], sb = stageBase[b], pb = payBase[b];
  int dst0 = b << BSH;
  h2[t] = 0;
  __syncthreads();
  for (int i = t; i < cnt; i += 256)
    atomicAdd(&h2[(stage[sb + i].y >> 17) & 255], 1);
  __syncthreads();
  int c = h2[t];
  invD[t] = (c > 0) ? (1.0f / (float)c) : 0.0f;
  int pc = (c + 3) & ~3;                    // row padded to x4
  ro[t] = pc;
  __syncthreads();
  for (int off = 1; off < 256; off <<= 1) {
    int a = (t >= off) ? ro[t - off] : 0;
    __syncthreads();
    ro[t] += a;
    __syncthreads();
  }
  int myoff = ro[t] - pc;                   // exclusive padded offset
  int n = dst0 + t;
  if (n < NT) { rowD[n] = pb + myoff; cntD[n] = c; }
  cur2[t] = myoff;
  __syncthreads();
  int cpL = (cnt + SLACK + 3) & ~3;         // flush exactly tiles pay (no gaps)
  for (int i = t; i < cpL; i += 256) buf[i] = make_int2(0, 0);
  __syncthreads();
  for (int i = t; i < cnt; i += 256) {
    int2 r = stage[sb + i];
    int dl = (r.y >> 17) & 255;
    float w = __uint_as_float((unsigned)r.x & 0xffff0000u);
    float wp = w * invD[dl];
    unsigned uw = __float_as_uint(wp);
    unsigned wb2 = (uw + 0x7fffu + ((uw >> 16) & 1u)) & 0xffff0000u;
    int p = atomicAdd(&cur2[dl], 1);
    buf[p] = make_int2((int)(wb2 | ((unsigned)r.x & 0xffffu)), r.y & 0x1ffff);
  }
  __syncthreads();
  for (int i = t; i < cpL; i += 256) pay[pb + i] = buf[i];
}

// ---- shared row-gather: 4 edges/iter, BRANCH-FREE pipeline (unchanged) ----
template<bool USE_WID>
__device__ __forceinline__ int pick_idx(const int4& q, int half) {
  int lo = USE_WID ? (q.x & 0xffff) : q.y;
  int hi = USE_WID ? (q.z & 0xffff) : q.w;
  return half ? hi : lo;
}
__device__ __forceinline__ void consume2(const int4& q, unsigned v, int half,
                                         float& a0, float& a1, float& a2, float& a3,
                                         float& sw) {
  int wm = half ? q.z : q.x;
  float w = __uint_as_float((unsigned)wm & 0xffff0000u);
  float4 x = dec4_e5m2(v);
  a0 = fmaf(w, x.x, a0); a1 = fmaf(w, x.y, a1);
  a2 = fmaf(w, x.z, a2); a3 = fmaf(w, x.w, a3);
  sw += w;
}

template<bool USE_WID>
__device__ __forceinline__ void gather_row(const int2* __restrict__ pay,
                                           const unsigned* __restrict__ tab,
                                           int beg, int cnt, int li, int half,
                                           float& a0, float& a1, float& a2, float& a3,
                                           float& sw) {
  int G = (cnt + 3) >> 2;                       // groups of 4 edges (rows padded)
  const int4* __restrict__ pp = (const int4*)(pay + beg);
  int4 q0a = pp[0], q0b = pp[1];
  int4 q1a = pp[2], q1b = pp[3];
  int4 q2a = pp[4], q2b = pp[5];
  int4 q3a = pp[6], q3b = pp[7];
  int4 q4a = pp[8], q4b = pp[9];
  unsigned va0 = tab[(size_t)pick_idx<USE_WID>(q0a, half) * 32 + li];
  unsigned vb0 = tab[(size_t)pick_idx<USE_WID>(q0b, half) * 32 + li];
  unsigned va1 = tab[(size_t)pick_idx<USE_WID>(q1a, half) * 32 + li];
  unsigned vb1 = tab[(size_t)pick_idx<USE_WID>(q1b, half) * 32 + li];
  unsigned va2 = tab[(size_t)pick_idx<USE_WID>(q2a, half) * 32 + li];
  unsigned vb2 = tab[(size_t)pick_idx<USE_WID>(q2b, half) * 32 + li];
  for (int g = 0; g < G; ++g) {
    unsigned vn0 = tab[(size_t)pick_idx<USE_WID>(q3a, half) * 32 + li];
    unsigned vn1 = tab[(size_t)pick_idx<USE_WID>(q3b, half) * 32 + li];
    int4 qna = pp[2 * g + 10];
    int4 qnb = pp[2 * g + 11];
    consume2(q0a, va0, half, a0, a1, a2, a3, sw);
    consume2(q0b, vb0, half, a0, a1, a2, a3, sw);
    q0a = q1a; q0b = q1b; q1a = q2a; q1b = q2b; q2a = q3a; q2b = q3b;
    q3a = q4a; q3b = q4b; q4a = qna; q4b = qnb;
    va0 = va1; vb0 = vb1; va1 = va2; vb1 = vb2; va2 = vn0; vb2 = vn1;
  }
}

// ---------- K7: layer-1 aggregate (w' folded mean) + leaky -> h1p8 ----------
__global__ void k_agg1(const int2* __restrict__ pay,
                       const int* __restrict__ rowD, const int* __restrict__ cntD,
                       const unsigned* __restrict__ P1p8,
                       unsigned* __restrict__ h1p8) {
  int n = blockIdx.x * 4 + (threadIdx.x >> 6);
  int lane = threadIdx.x & 63;
  int li = lane & 31, half = lane >> 5;
  int beg = __builtin_amdgcn_readfirstlane(rowD[n]);
  int cnt = __builtin_amdgcn_readfirstlane(cntD[n]);
  float a0 = 0.f, a1 = 0.f, a2 = 0.f, a3 = 0.f, sw = 0.f;
  gather_row<true>(pay, P1p8, beg, cnt, li, half, a0, a1, a2, a3, sw);
  a0 += __shfl_down(a0, 32);
  a1 += __shfl_down(a1, 32);
  a2 += __shfl_down(a2, 32);
  a3 += __shfl_down(a3, 32);
  if (lane < 32) {
    float x0 = a0, x1 = a1, x2 = a2, x3 = a3;   // w'=w/deg -> already the mean
    x0 = (x0 > 0.f) ? x0 : 0.01f * x0;     // leaky_relu(0)=0 keeps deg==0 rows 0
    x1 = (x1 > 0.f) ? x1 : 0.01f * x1;
    x2 = (x2 > 0.f) ? x2 : 0.01f * x2;
    x3 = (x3 > 0.f) ? x3 : 0.01f * x3;
    h1p8[(size_t)n * 32 + li] = enc4_e5m2(x0, x1, x2, x3);
  }
}

// ---------- K8: layer-2 per-node gather fused with per-graph pooling ----------
// R9-proven geometry: NPW2=10, 2500 blocks (10k waves) — rides the ~1.45 TB/s
// random-line L2-fill ceiling (FETCH is at its compulsory ~90 MB floor).
#define NPW2 10
#define BLKS_PER_G (NODES_PER_GRAPH / (4 * NPW2))   // 50
__global__ void k_agg2(const int2* __restrict__ pay,
                       const int* __restrict__ rowD, const int* __restrict__ cntD,
                       const unsigned* __restrict__ h1p8,
                       float* __restrict__ pool) {
  int g = blockIdx.x / BLKS_PER_G;
  int chunk = blockIdx.x % BLKS_PER_G;
  int w = threadIdx.x >> 6, lane = threadIdx.x & 63;
  int li = lane & 31, half = lane >> 5;
  int nbase = g * NODES_PER_GRAPH + chunk * (4 * NPW2) + w * NPW2;
  float s0 = 0.f, s1 = 0.f, s2 = 0.f, s3 = 0.f, sc = 0.f;
  for (int i = 0; i < NPW2; ++i) {
    int n = nbase + i;
    int beg = __builtin_amdgcn_readfirstlane(rowD[n]);
    int cnt = __builtin_amdgcn_readfirstlane(cntD[n]);
    gather_row<false>(pay, h1p8, beg, cnt, li, half, s0, s1, s2, s3, sc);
  }
  s0 += __shfl_down(s0, 32);
  s1 += __shfl_down(s1, 32);
  s2 += __shfl_down(s2, 32);
  s3 += __shfl_down(s3, 32);
  sc += __shfl_down(sc, 32);
  __shared__ float sS[4 * 128];
  __shared__ float sC[4];
  if (lane < 32) {
    sS[w * 128 + 4 * li + 0] = s0;
    sS[w * 128 + 4 * li + 1] = s1;
    sS[w * 128 + 4 * li + 2] = s2;
    sS[w * 128 + 4 * li + 3] = s3;
  }
  if (lane == 0) sC[w] = sc;
  __syncthreads();
  int t = threadIdx.x;
  if (t < 128) {
    float v = sS[t] + sS[128 + t] + sS[256 + t] + sS[384 + t];
    atomicAdd(&pool[g * D + t], v);
  }
  if (t == 0) atomicAdd(&pool[B_GRAPHS * D + g], sC[0] + sC[1] + sC[2] + sC[3]);
}

// ---------- K9: head ----------
__global__ void k_final(const float* __restrict__ poolS, const float* __restrict__ poolC,
                        const float* __restrict__ W2, const float* __restrict__ b2,
                        const float* __restrict__ W_out, const float* __restrict__ b_out,
                        const float* __restrict__ y, float* __restrict__ out) {
  int t = threadIdx.x;  // 128 threads
  __shared__ float w2o[D];
  __shared__ float red[D];
  __shared__ float s2o_sh;
  __shared__ float logits[B_GRAPHS];
  float acc = 0.f;
  for (int d = 0; d < D; ++d) acc = fmaf(W2[t * D + d], W_out[d], acc);
  w2o[t] = acc;
  red[t] = b2[t] * W_out[t];
  __syncthreads();
  for (int off = 64; off > 0; off >>= 1) {
    if (t < off) red[t] += red[t + off];
    __syncthreads();
  }
  if (t == 0) s2o_sh = red[0];
  __syncthreads();
  float s2o = s2o_sh;
  float bout = b_out[0];
  const float invN = 1.0f / (float)NODES_PER_GRAPH;
  for (int g = 0; g < B_GRAPHS; ++g) {
    red[t] = poolS[g * D + t] * w2o[t];
    __syncthreads();
    for (int off = 64; off > 0; off >>= 1) {
      if (t < off) red[t] += red[t + off];
      __syncthreads();
    }
    if (t == 0) logits[g] = red[0] * invN + poolC[g] * invN * s2o + bout;
    __syncthreads();
  }
  float term = 0.f;
  if (t < B_GRAPHS) {
    float l = logits[t];
    out[1 + t] = 1.0f / (1.0f + expf(-l));            // y_pred
    term = fmaxf(l, 0.f) - l * y[t] + log1pf(expf(-fabsf(l)));
  }
  red[t] = term;
  __syncthreads();
  for (int off = 64; off > 0; off >>= 1) {
    if (t < off) red[t] += red[t + off];
    __syncthreads();
  }
  if (t == 0) out[0] = red[0] / (float)B_GRAPHS;      // loss
}

extern "C" void kernel_launch(void* const* d_in, const int* in_sizes, int n_in,
                              void* d_out, int out_size, void* d_ws, size_t ws_size,
                              hipStream_t stream) {
  const int*   node_ids = (const int*)d_in[0];
  const int*   src      = (const int*)d_in[1];
  const int*   dst      = (const int*)d_in[2];
  const float* ew       = (const float*)d_in[3];
  const float* y        = (const float*)d_in[4];
  const float* embeds   = (const float*)d_in[5];
  const float* W1       = (const float*)d_in[6];
  const float* b1       = (const float*)d_in[7];
  const float* W2       = (const float*)d_in[8];
  const float* b2       = (const float*)d_in[9];
  const float* W_out    = (const float*)d_in[10];
  const float* b_out    = (const float*)d_in[11];
  float* out = (float*)d_out;
  (void)in_sizes; (void)n_in; (void)out_size; (void)ws_size;

  char* ws = (char*)d_ws;
  size_t off = 0;
  auto alloc = [&](size_t bytes) {
    size_t r = off;
    off = (off + bytes + 511) & ~(size_t)511;
    return r;
  };
  // zero region (poisoned 0xAA before every call)
  size_t o_binCnt = alloc(512 * 4);
  size_t o_binCur = alloc(512 * 4);
  size_t o_pool   = alloc((size_t)POOL_N * 4);
  size_t zero_end = off;
  // non-zeroed
  size_t o_sBase  = alloc(512 * 4);
  size_t o_pBase  = alloc(512 * 4);
  size_t o_rowD   = alloc((size_t)(NT + 1) * 4);
  size_t o_cntD   = alloc((size_t)NT * 4);
  size_t o_P1p8   = alloc((size_t)V * 32 * 4);          // 1.92 MB
  size_t o_h1p8   = alloc((size_t)NT * 32 * 4);         // 12.8 MB
  size_t o_stage  = alloc((size_t)NE * 8);              // 12.8 MB
  size_t o_pay    = alloc((size_t)PAY_CAP2 * 8);        // 15.2 MB

  int*      binCnt   = (int*)(ws + o_binCnt);
  int*      binCursor= (int*)(ws + o_binCur);
  float*    pool     = (float*)(ws + o_pool);
  int*      stageBase= (int*)(ws + o_sBase);
  int*      payBase  = (int*)(ws + o_pBase);
  int*      rowD     = (int*)(ws + o_rowD);
  int*      cntD     = (int*)(ws + o_cntD);
  unsigned* P1p8     = (unsigned*)(ws + o_P1p8);
  unsigned* h1p8     = (unsigned*)(ws + o_h1p8);
  int2*     stage    = (int2*)(ws + o_stage);
  int2*     pay      = (int2*)(ws + o_pay);

  hipMemsetAsync(ws, 0, zero_end, stream);
  // zero the pay tail (prologue overrun past rowD[NT] reads into it)
  hipMemsetAsync(pay + (PAY_CAP2 - 512), 0, 512 * 8, stream);

  k_project<<<(V + PR - 1) / PR, 256, 0, stream>>>(embeds, W1, b1, P1p8);
  k_hist<<<NFB, 512, 0, stream>>>(dst, binCnt);
  k_binscan<<<1, 512, 0, stream>>>(binCnt, stageBase, payBase, rowD);
  k_binfill<<<NFB, 512, 0, stream>>>(src, dst, ew, node_ids,
                                     stageBase, binCursor, stage);
  k_binsort<<<NBIN, 256, 0, stream>>>(stage, binCnt, stageBase, payBase,
                                      rowD, cntD, pay);
  k_agg1<<<NT / 4, 256, 0, stream>>>(pay, rowD, cntD, P1p8, h1p8);
  k_agg2<<<B_GRAPHS * BLKS_PER_G, 256, 0, stream>>>(pay, rowD, cntD, h1p8, pool);
  k_final<<<1, 128, 0, stream>>>(pool, pool + B_GRAPHS * D, W2, b2, W_out, b_out, y, out);
}